// Round 1
// baseline (415.743 us; speedup 1.0000x reference)
//
#include <hip/hip_runtime.h>

// FNet 2D FFT real part: x[8][4096][768] fp32 -> Re(FFT_seq(FFT_hidden(x)))
// Pass 1: FFT-768 along hidden per row, write complex transposed [b][k2][n1]
//         (Re plane -> ws, Im plane -> d_out used as scratch)
// Pass 2: FFT-4096 along n1 per (b,k2) row (contiguous), write Re in place over ws
// Pass 3: transpose ws [b][k2][k1] -> d_out [b][k1][k2]

constexpr int HN = 768;
constexpr int SN = 4096;
constexpr int R1 = 4;              // rows per block, pass 1
constexpr float PI2 = 6.283185307179586f;

static __device__ __forceinline__ float2 cadd(float2 a, float2 b) { return make_float2(a.x + b.x, a.y + b.y); }
static __device__ __forceinline__ float2 csub(float2 a, float2 b) { return make_float2(a.x - b.x, a.y - b.y); }
static __device__ __forceinline__ float2 cmul(float2 a, float2 b) { return make_float2(a.x * b.x - a.y * b.y, a.x * b.y + a.y * b.x); }

static __device__ __forceinline__ void bfly4(float2 v0, float2 v1, float2 v2, float2 v3,
                                             float2& V0, float2& V1, float2& V2, float2& V3) {
  float2 t0 = cadd(v0, v2), t1 = csub(v0, v2);
  float2 t2 = cadd(v1, v3), t3 = csub(v1, v3);
  float2 t3i = make_float2(t3.y, -t3.x);   // -i * t3  (omega_4 = e^{-2pi i/4})
  V0 = cadd(t0, t2); V2 = csub(t0, t2);
  V1 = cadd(t1, t3i); V3 = csub(t1, t3i);
}

// ---------------- Pass 1: hidden FFT (768 = 3 * 4^4), Stockham ----------------
__global__ __launch_bounds__(256)
void fft_hidden(const float* __restrict__ x, float* __restrict__ wRe, float* __restrict__ wIm) {
  __shared__ float2 bufA[R1 * HN];
  __shared__ float2 bufB[R1 * HN];
  const int tid = threadIdx.x;
  const int blk = blockIdx.x;           // 8192 blocks
  const int b = blk & 7;                // == xcd heuristic: batch pinned per XCD
  const int tile = blk >> 3;            // 0..1023
  const int n0 = tile * R1;
  const float* xin = x + ((size_t)b * SN + n0) * HN;

  for (int i = tid; i < R1 * HN; i += 256)
    bufA[i] = make_float2(xin[i], 0.0f);
  __syncthreads();

  float2* src = bufA;
  float2* dst = bufB;

  // Stage 1: radix-3, Ns = 1 (no twiddle)
  {
    const int NR = HN / 3;  // 256
    for (int w = tid; w < R1 * NR; w += 256) {
      const int row = w >> 8;
      const int j = w & 255;
      const float2* s = src + row * HN;
      float2* d = dst + row * HN;
      float2 v0 = s[j], v1 = s[j + NR], v2 = s[j + 2 * NR];
      float tr = v1.x + v2.x, ti = v1.y + v2.y;
      float ur = v1.x - v2.x, ui = v1.y - v2.y;
      const float cc = -0.5f, ss = -0.8660254037844386f;  // omega_3 = cc + i*ss
      d[3 * j]     = make_float2(v0.x + tr, v0.y + ti);
      d[3 * j + 1] = make_float2(v0.x + cc * tr - ss * ui, v0.y + cc * ti + ss * ur);
      d[3 * j + 2] = make_float2(v0.x + cc * tr + ss * ui, v0.y + cc * ti - ss * ur);
    }
    __syncthreads();
    float2* t = src; src = dst; dst = t;
  }

  // Stages 2..5: radix-4, Ns = 3, 12, 48, 192
  int Ns = 3;
  for (int st = 0; st < 4; ++st) {
    const int NR = HN / 4;  // 192
    for (int w = tid; w < R1 * NR; w += 256) {
      const int row = w / NR;
      const int j = w - row * NR;
      const float2* s = src + row * HN;
      float2* d = dst + row * HN;
      float2 v0 = s[j], v1 = s[j + NR], v2 = s[j + 2 * NR], v3 = s[j + 3 * NR];
      const int jm = j % Ns;
      float ang = -PI2 * (float)jm / (float)(4 * Ns);
      float s1, c1; __sincosf(ang, &s1, &c1);
      float2 w1 = make_float2(c1, s1);
      float2 w2 = cmul(w1, w1);
      float2 w3 = cmul(w2, w1);
      v1 = cmul(v1, w1); v2 = cmul(v2, w2); v3 = cmul(v3, w3);
      float2 V0, V1, V2, V3;
      bfly4(v0, v1, v2, v3, V0, V1, V2, V3);
      const int idxD = (j / Ns) * (Ns * 4) + jm;
      d[idxD] = V0; d[idxD + Ns] = V1; d[idxD + 2 * Ns] = V2; d[idxD + 3 * Ns] = V3;
    }
    __syncthreads();
    float2* t = src; src = dst; dst = t;
    Ns *= 4;
  }

  // Transposed store: [b][k2][n1], Re -> wRe, Im -> wIm. 16B chunks per k2.
  for (int i = tid; i < R1 * HN; i += 256) {
    const int k2 = i >> 2;
    const int r = i & 3;
    float2 v = src[r * HN + k2];
    const size_t o = ((size_t)b * HN + k2) * SN + n0 + r;
    wRe[o] = v.x;
    wIm[o] = v.y;
  }
}

// ---------------- Pass 2: seq FFT (4096 = 4^6), Stockham, Re output in place ----------------
__global__ __launch_bounds__(1024)
void fft_seq(float* __restrict__ wRe, const float* __restrict__ wIm) {
  __shared__ float2 bufA[SN];  // 32 KB
  __shared__ float2 bufB[SN];  // 32 KB
  const int tid = threadIdx.x;
  const int blk = blockIdx.x;                 // 6144 blocks
  const int col = (blk & 7) * 768 + (blk >> 3);  // b = blk&7, k2 = blk>>3
  const size_t base = (size_t)col * SN;

  for (int i = tid; i < SN; i += 1024)
    bufA[i] = make_float2(wRe[base + i], wIm[base + i]);
  __syncthreads();

  float2* src = bufA;
  float2* dst = bufB;
  int Ns = 1;
  for (int st = 0; st < 6; ++st) {
    const int j = tid;  // exactly N/4 = 1024 butterflies
    float2 v0 = src[j], v1 = src[j + 1024], v2 = src[j + 2048], v3 = src[j + 3072];
    const int jm = j & (Ns - 1);
    float ang = -PI2 * (float)jm / (float)(4 * Ns);
    float s1, c1; __sincosf(ang, &s1, &c1);
    float2 w1 = make_float2(c1, s1);
    float2 w2 = cmul(w1, w1);
    float2 w3 = cmul(w2, w1);
    v1 = cmul(v1, w1); v2 = cmul(v2, w2); v3 = cmul(v3, w3);
    float2 V0, V1, V2, V3;
    bfly4(v0, v1, v2, v3, V0, V1, V2, V3);
    const int idxD = ((j & ~(Ns - 1)) << 2) + jm;
    dst[idxD] = V0; dst[idxD + Ns] = V1; dst[idxD + 2 * Ns] = V2; dst[idxD + 3 * Ns] = V3;
    __syncthreads();
    float2* t = src; src = dst; dst = t;
    Ns <<= 2;
  }

  for (int i = tid; i < SN; i += 1024)
    wRe[base + i] = src[i].x;
}

// ---------------- Pass 3: transpose [b][k2][k1] -> [b][k1][k2] ----------------
__global__ __launch_bounds__(256)
void transpose_out(const float* __restrict__ in, float* __restrict__ out) {
  __shared__ float tile[32][33];
  const int b = blockIdx.z;
  const int k1_0 = blockIdx.x * 32;
  const int k2_0 = blockIdx.y * 32;
  const float* ib = in + (size_t)b * HN * SN;
  float* ob = out + (size_t)b * SN * HN;
  const int tx = threadIdx.x;   // 0..31
  const int ty = threadIdx.y;   // 0..7
#pragma unroll
  for (int i = 0; i < 32; i += 8)
    tile[ty + i][tx] = ib[(size_t)(k2_0 + ty + i) * SN + k1_0 + tx];
  __syncthreads();
#pragma unroll
  for (int i = 0; i < 32; i += 8)
    ob[(size_t)(k1_0 + ty + i) * HN + k2_0 + tx] = tile[tx][ty + i];
}

extern "C" void kernel_launch(void* const* d_in, const int* in_sizes, int n_in,
                              void* d_out, int out_size, void* d_ws, size_t ws_size,
                              hipStream_t stream) {
  const float* x = (const float*)d_in[0];
  float* out = (float*)d_out;
  float* wRe = (float*)d_ws;   // 8*768*4096 floats = 100.7 MB
  float* wIm = out;            // reuse output buffer as Im scratch (dead after pass 2)

  fft_hidden<<<8192, 256, 0, stream>>>(x, wRe, wIm);
  fft_seq<<<6144, 1024, 0, stream>>>(wRe, wIm);
  transpose_out<<<dim3(SN / 32, HN / 32, 8), dim3(32, 8, 1), 0, stream>>>(wRe, out);
}

// Round 2
// 269.017 us; speedup vs baseline: 1.5454x; 1.5454x over previous
//
#include <hip/hip_runtime.h>

// FNet 2D FFT real part, Hermitian-optimized 3-pass plan.
// x[8][4096][768] fp32 -> Re(FFT2(x)) over (seq, hidden).
//
// Pass 1 (fft_hidden): pack row pairs z = x[2r] + i*x[2r+1], one 768-pt FFT per
//   pair, unpack via conjugate symmetry, keep only k2 in [0,384], store
//   transposed planes [b][k2][n1]: Re->ws, Im->d_out (scratch).
// Pass 2 (fft_seq): 4096-pt FFT per (b,k2) row, in-place single LDS buffer,
//   write Re over the ws row.
// Pass 3 (transpose_mirror): ws[b][k2'][k1] -> out[b][k1][k2'] plus the
//   Hermitian mirror out[b][(4096-k1)%4096][768-k2'] for k2' in [1,383].

constexpr int HN = 768;
constexpr int SN = 4096;
constexpr int KH = 385;   // Hermitian-unique hidden frequencies 0..384
constexpr float PI2 = 6.283185307179586f;

static __device__ __forceinline__ float2 cadd(float2 a, float2 b) { return make_float2(a.x + b.x, a.y + b.y); }
static __device__ __forceinline__ float2 csub(float2 a, float2 b) { return make_float2(a.x - b.x, a.y - b.y); }
static __device__ __forceinline__ float2 cmul(float2 a, float2 b) { return make_float2(a.x * b.x - a.y * b.y, a.x * b.y + a.y * b.x); }

static __device__ __forceinline__ void bfly4(float2 v0, float2 v1, float2 v2, float2 v3,
                                             float2& V0, float2& V1, float2& V2, float2& V3) {
  float2 t0 = cadd(v0, v2), t1 = csub(v0, v2);
  float2 t2 = cadd(v1, v3), t3 = csub(v1, v3);
  float2 t3i = make_float2(t3.y, -t3.x);   // -i * t3
  V0 = cadd(t0, t2); V2 = csub(t0, t2);
  V1 = cadd(t1, t3i); V3 = csub(t1, t3i);
}

// ---------------- Pass 1: hidden FFT (768 = 3 * 4^4), 2 packed complex rows = 4 real rows ----------------
__global__ __launch_bounds__(256)
void fft_hidden(const float* __restrict__ x, float* __restrict__ wRe, float* __restrict__ wIm) {
  __shared__ float2 bufA[2 * HN];   // 12 KB
  __shared__ float2 bufB[2 * HN];   // 12 KB
  const int tid = threadIdx.x;
  const int blk = blockIdx.x;       // 8192 blocks
  const int b = blk & 7;            // batch pinned per XCD
  const int n0 = (blk >> 3) * 4;    // first of 4 real rows
  const float* xb = x + (size_t)b * SN * HN;

  // Load 4 real rows packed into 2 complex rows: z_p[n] = x[n0+2p][n] + i x[n0+2p+1][n]
  for (int i = tid; i < 2 * HN; i += 256) {
    const int p = i / HN;
    const int n = i - p * HN;
    const size_t r = (size_t)(n0 + 2 * p) * HN + n;
    bufA[i] = make_float2(xb[r], xb[r + HN]);
  }
  __syncthreads();

  float2* src = bufA;
  float2* dst = bufB;

  // Stage 1: radix-3, Ns = 1 (no twiddle). 2 rows x 256 butterflies = 512 items.
  {
    for (int w = tid; w < 512; w += 256) {
      const int row = w >> 8;
      const int j = w & 255;
      const float2* s = src + row * HN;
      float2* d = dst + row * HN;
      float2 v0 = s[j], v1 = s[j + 256], v2 = s[j + 512];
      float tr = v1.x + v2.x, ti = v1.y + v2.y;
      float ur = v1.x - v2.x, ui = v1.y - v2.y;
      const float cc = -0.5f, ss = -0.8660254037844386f;
      d[3 * j]     = make_float2(v0.x + tr, v0.y + ti);
      d[3 * j + 1] = make_float2(v0.x + cc * tr - ss * ui, v0.y + cc * ti + ss * ur);
      d[3 * j + 2] = make_float2(v0.x + cc * tr + ss * ui, v0.y + cc * ti - ss * ur);
    }
    __syncthreads();
    float2* t = src; src = dst; dst = t;
  }

  // Stages 2..5: radix-4, Ns = 3, 12, 48, 192. 2 rows x 192 butterflies = 384 items.
  int Ns = 3;
  for (int st = 0; st < 4; ++st) {
    for (int w = tid; w < 384; w += 256) {
      const int row = w / 192;
      const int j = w - row * 192;
      const float2* s = src + row * HN;
      float2* d = dst + row * HN;
      float2 v0 = s[j], v1 = s[j + 192], v2 = s[j + 384], v3 = s[j + 576];
      const int jm = j % Ns;
      float ang = -PI2 * (float)jm / (float)(4 * Ns);
      float s1, c1; __sincosf(ang, &s1, &c1);
      float2 w1 = make_float2(c1, s1);
      float2 w2 = cmul(w1, w1);
      float2 w3 = cmul(w2, w1);
      v1 = cmul(v1, w1); v2 = cmul(v2, w2); v3 = cmul(v3, w3);
      float2 V0, V1, V2, V3;
      bfly4(v0, v1, v2, v3, V0, V1, V2, V3);
      const int idxD = (j / Ns) * (Ns * 4) + jm;
      d[idxD] = V0; d[idxD + Ns] = V1; d[idxD + 2 * Ns] = V2; d[idxD + 3 * Ns] = V3;
    }
    __syncthreads();
    float2* t = src; src = dst; dst = t;
    Ns *= 4;
  }

  // Unpack conjugate symmetry + transposed Hermitian store (k2 in [0,384]).
  // Y_{2p}[k]   = (Z_p[k] + conj Z_p[768-k]) / 2
  // Y_{2p+1}[k] = (Z_p[k] - conj Z_p[768-k]) / (2i)
  for (int k = tid; k < KH; k += 256) {
    const int km = (k == 0) ? 0 : (HN - k);
    float2 Z0 = src[k],      Z0m = src[km];
    float2 Z1 = src[HN + k], Z1m = src[HN + km];
    float4 re, im;
    re.x = 0.5f * (Z0.x + Z0m.x);  im.x = 0.5f * (Z0.y - Z0m.y);
    re.y = 0.5f * (Z0.y + Z0m.y);  im.y = 0.5f * (Z0m.x - Z0.x);
    re.z = 0.5f * (Z1.x + Z1m.x);  im.z = 0.5f * (Z1.y - Z1m.y);
    re.w = 0.5f * (Z1.y + Z1m.y);  im.w = 0.5f * (Z1m.x - Z1.x);
    const size_t o = (((size_t)(b * KH + k)) * SN + n0) >> 2;  // float4 index, n0 % 4 == 0
    ((float4*)wRe)[o] = re;
    ((float4*)wIm)[o] = im;
  }
}

// ---------------- Pass 2: seq FFT (4096 = 4^6), in-place single buffer, 512 threads ----------------
__global__ __launch_bounds__(512)
void fft_seq(float* __restrict__ wRe, const float* __restrict__ wIm) {
  __shared__ float2 buf[SN];   // 32 KB -> 4 blocks/CU (thread-limited), 100% occupancy
  const int tid = threadIdx.x;
  const int blk = blockIdx.x;              // 3080 blocks = 8 * 385
  const int b = blk & 7;
  const int k2 = blk >> 3;
  const size_t base = ((size_t)b * KH + k2) * SN;

  for (int i = tid; i < SN; i += 512)
    buf[i] = make_float2(wRe[base + i], wIm[base + i]);
  __syncthreads();

  int Ns = 1;
  for (int st = 0; st < 6; ++st) {
    float2 V[2][4];
    int idxD[2];
#pragma unroll
    for (int t = 0; t < 2; ++t) {
      const int j = tid + t * 512;
      float2 v0 = buf[j], v1 = buf[j + 1024], v2 = buf[j + 2048], v3 = buf[j + 3072];
      const int jm = j & (Ns - 1);
      float ang = -PI2 * (float)jm / (float)(4 * Ns);
      float s1, c1; __sincosf(ang, &s1, &c1);
      float2 w1 = make_float2(c1, s1);
      float2 w2 = cmul(w1, w1);
      float2 w3 = cmul(w2, w1);
      v1 = cmul(v1, w1); v2 = cmul(v2, w2); v3 = cmul(v3, w3);
      bfly4(v0, v1, v2, v3, V[t][0], V[t][1], V[t][2], V[t][3]);
      idxD[t] = ((j & ~(Ns - 1)) << 2) + jm;
    }
    __syncthreads();   // all reads done before any in-place writes
#pragma unroll
    for (int t = 0; t < 2; ++t) {
      buf[idxD[t]] = V[t][0];
      buf[idxD[t] + Ns] = V[t][1];
      buf[idxD[t] + 2 * Ns] = V[t][2];
      buf[idxD[t] + 3 * Ns] = V[t][3];
    }
    __syncthreads();
    Ns <<= 2;
  }

  for (int i = tid; i < SN; i += 512)
    wRe[base + i] = buf[i].x;
}

// ---------------- Pass 3: transpose + Hermitian mirror ----------------
// ws[b][k2'][k1] (k2' in [0,384]) -> out[b][k1][k2'] and out[b][(4096-k1)%4096][768-k2']
__global__ __launch_bounds__(256)
void transpose_mirror(const float* __restrict__ ws, float* __restrict__ out) {
  __shared__ float tile[32][33];
  const int b = blockIdx.z;
  const int k1_0 = blockIdx.x * 32;
  const int k2_0 = blockIdx.y * 32;
  const float* ib = ws + (size_t)b * KH * SN;
  float* ob = out + (size_t)b * SN * HN;
  const int tx = threadIdx.x;   // 0..31
  const int ty = threadIdx.y;   // 0..7
#pragma unroll
  for (int i = 0; i < 32; i += 8) {
    const int k2 = k2_0 + ty + i;
    tile[ty + i][tx] = (k2 < KH) ? ib[(size_t)k2 * SN + k1_0 + tx] : 0.0f;
  }
  __syncthreads();
  const int k2 = k2_0 + tx;
#pragma unroll
  for (int i = 0; i < 32; i += 8) {
    const int k1 = k1_0 + ty + i;
    const float v = tile[tx][ty + i];
    if (k2 < KH)
      ob[(size_t)k1 * HN + k2] = v;
    if (k2 >= 1 && k2 <= HN - KH)   // k2' in [1,383] -> mirror column 768-k2' in [385,767]
      ob[(size_t)((SN - k1) & (SN - 1)) * HN + (HN - k2)] = v;
  }
}

extern "C" void kernel_launch(void* const* d_in, const int* in_sizes, int n_in,
                              void* d_out, int out_size, void* d_ws, size_t ws_size,
                              hipStream_t stream) {
  const float* x = (const float*)d_in[0];
  float* out = (float*)d_out;
  float* wRe = (float*)d_ws;   // 8*385*4096 floats = 50.5 MB (<= ws_size used last round)
  float* wIm = out;            // reuse output buffer as Im scratch (dead after pass 2)

  fft_hidden<<<8192, 256, 0, stream>>>(x, wRe, wIm);
  fft_seq<<<3080, 512, 0, stream>>>(wRe, wIm);
  transpose_mirror<<<dim3(SN / 32, (KH + 31) / 32, 8), dim3(32, 8, 1), 0, stream>>>(wRe, out);
}